// Round 3
// baseline (416.472 us; speedup 1.0000x reference)
//
#include <hip/hip_runtime.h>

#define B_   64
#define L_   2048
#define D_   512
#define SEG_ 16         // segments over L for the two gather phases
#define RPS_ 128        // rows per segment (L_/SEG_)
#define NS_  4          // LDS ring slots per wave (2KB fp32 row each)
#define NB_  512        // grid blocks; needs 2/CU co-resident (LDS allows 4/CU)

// counted vmem wait; "memory" clobber keeps following ds_read from hoisting
#define WAITVM(N) asm volatile("s_waitcnt vmcnt(" #N ")" ::: "memory")

// async global->LDS DMA: 16B/lane, 64 lanes -> 1KB per call
__device__ __forceinline__ void gl2lds(const float* g, float* l) {
  __builtin_amdgcn_global_load_lds(
      (const __attribute__((address_space(1))) void*)g,
      (__attribute__((address_space(3))) void*)l, 16, 0, 0);
}

// DPP add step: x += dpp_move(x, C); bound_ctrl -> invalid lanes contribute 0
template <int C>
__device__ __forceinline__ float dpp_add(float x) {
  int y = __builtin_amdgcn_update_dpp(0, __builtin_bit_cast(int, x), C, 0xf, 0xf, true);
  return x + __builtin_bit_cast(float, y);
}

// full 64-lane sum, VALU-pipe only; uniform result via readlane 63
__device__ __forceinline__ float wave_sum_u(float x) {
  x = dpp_add<0x111>(x);   // row_shr:1
  x = dpp_add<0x112>(x);   // row_shr:2
  x = dpp_add<0x114>(x);   // row_shr:4
  x = dpp_add<0x118>(x);   // row_shr:8
  x = dpp_add<0x142>(x);   // row_bcast15
  x = dpp_add<0x143>(x);   // row_bcast31 -> lane 63 has full sum
  return __builtin_bit_cast(float, __builtin_amdgcn_readlane(__builtin_bit_cast(int, x), 63));
}

__device__ __forceinline__ float dot8(float4 e0, float4 e1, float4 a0, float4 a1) {
  return e0.x * a0.x + e0.y * a0.y + e0.z * a0.z + e0.w * a0.w +
         e1.x * a1.x + e1.y * a1.y + e1.z * a1.z + e1.w * a1.w;
}

// tail-drain schedule for NS_=4 ring with 2 loads/row
__device__ __forceinline__ void ring_wait(int i) {
  if (i <= 28)      WAITVM(6);
  else if (i == 29) WAITVM(4);
  else if (i == 30) WAITVM(2);
  else              WAITVM(0);
}

// grid barrier; all NB_ blocks are co-resident (2/CU needed, 4/CU possible)
__device__ __forceinline__ void gbar(unsigned* c) {
  __syncthreads();
  if (threadIdx.x == 0) {
    __threadfence();                       // release my writes (device scope)
    atomicAdd(c, 1u);
    while (atomicAdd(c, 0u) < (unsigned)NB_) __builtin_amdgcn_s_sleep(2);
    __threadfence();                       // acquire others' writes
  }
  __syncthreads();
}

extern "C" __global__ __launch_bounds__(256, 2) void k_fused(
    const int* __restrict__ tok, const float* __restrict__ emb,
    const float* __restrict__ Wb, float* __restrict__ A,
    float* __restrict__ v, float* __restrict__ ms,
    float* __restrict__ out, unsigned* __restrict__ bar) {
  const int bid = blockIdx.x;
  const int t = threadIdx.x, w = t >> 6, lane = t & 63;
  __shared__ __align__(16) float stag[4 * NS_ * D_];   // 32 KB ring / scratch overlay
  __shared__ float red[4][2];

  // ---------------- phase A: per-segment partial sums of E (for h) ----------
  for (int task = 0; task < 2; ++task) {
    const int id = bid + task * NB_;          // 1024 (seg,b) tasks
    const int seg = id & (SEG_ - 1), b = id >> 4;
    float* wsl = stag + w * (NS_ * D_);
    const int tokv = tok[b * L_ + seg * RPS_ + w * 32 + (lane & 31)];
    float acc[8];
#pragma unroll
    for (int j = 0; j < 8; ++j) acc[j] = 0.f;
#pragma unroll
    for (int i = 0; i < NS_; ++i) {
      const size_t row = (size_t)(__builtin_amdgcn_readlane(tokv, i) + 1);
      const float* rp = emb + row * D_ + lane * 4;
      gl2lds(rp, wsl + i * D_);
      gl2lds(rp + 256, wsl + i * D_ + 256);
    }
#pragma unroll
    for (int i = 0; i < 32; ++i) {
      ring_wait(i);
      const float4* sp = (const float4*)(wsl + (i & (NS_ - 1)) * D_);
      const float4 e0 = sp[lane];
      const float4 e1 = sp[lane + 64];
      acc[0] += e0.x; acc[1] += e0.y; acc[2] += e0.z; acc[3] += e0.w;
      acc[4] += e1.x; acc[5] += e1.y; acc[6] += e1.z; acc[7] += e1.w;
      if (i + NS_ < 32) {
        const size_t row = (size_t)(__builtin_amdgcn_readlane(tokv, i + NS_) + 1);
        const float* rp = emb + row * D_ + lane * 4;
        float* sl = wsl + (i & (NS_ - 1)) * D_;
        gl2lds(rp, sl);
        gl2lds(rp + 256, sl + 256);
      }
    }
    __syncthreads();                          // all waves' rings idle
    float* buf = stag;                        // overlay: 4 x D_ combine buffer
#pragma unroll
    for (int j = 0; j < 4; ++j) {
      buf[w * D_ + lane * 4 + j]       = acc[j];
      buf[w * D_ + 256 + lane * 4 + j] = acc[4 + j];
    }
    __syncthreads();
    const int c = 2 * t;
    const float s0 = buf[c] + buf[D_ + c] + buf[2 * D_ + c] + buf[3 * D_ + c];
    const float s1 = buf[c + 1] + buf[D_ + c + 1] + buf[2 * D_ + c + 1] + buf[3 * D_ + c + 1];
    float* o = A + ((size_t)seg * B_ + b) * D_;
    o[c] = s0; o[c + 1] = s1;
    __syncthreads();                          // combine reads done before reuse
  }
  gbar(bar + 0);

  // ---------------- phase B: v[b] = W_b @ h[b] / L ----------
  {
    const int g = bid & 7, b = bid >> 3;      // 512 tasks, one per block
    float* sh = stag;                         // overlay: h[b] (2 KB)
    float s0 = 0.f, s1 = 0.f;
#pragma unroll
    for (int s = 0; s < SEG_; ++s) {
      const float* hp = A + ((size_t)s * B_ + b) * D_;
      s0 += hp[2 * t]; s1 += hp[2 * t + 1];
    }
    sh[2 * t] = s0; sh[2 * t + 1] = s1;
    __syncthreads();
    const float4* shv = (const float4*)sh;
    const float4 a0 = shv[lane];
    const float4 a1 = shv[lane + 64];
    const int d0 = g * 64 + w * 16;
#pragma unroll 4
    for (int i = 0; i < 16; ++i) {
      const int d = d0 + i;
      const float4* rp = (const float4*)(Wb + (size_t)d * D_);
      const float r = wave_sum_u(dot8(rp[lane], rp[lane + 64], a0, a1));
      if (lane == 0) v[(size_t)b * D_ + d] = r * (1.f / (float)L_);
    }
  }
  gbar(bar + 1);

  // ---------------- phase C: fused scores+softmax+weighted-sum ----------
  for (int task = 0; task < 2; ++task) {
    const int id = bid + task * NB_;
    const int seg = id & (SEG_ - 1), b = id >> 4;
    float* wsl = stag + w * (NS_ * D_);
    const int tokv = tok[b * L_ + seg * RPS_ + w * 32 + (lane & 31)];
    const float4* vv = (const float4*)(v + (size_t)b * D_);
    const float4 a0 = vv[lane];
    const float4 a1 = vv[lane + 64];
    float m = -1e30f, s = 0.f;
    float acc[8];
#pragma unroll
    for (int j = 0; j < 8; ++j) acc[j] = 0.f;
#pragma unroll
    for (int i = 0; i < NS_; ++i) {
      const size_t row = (size_t)(__builtin_amdgcn_readlane(tokv, i) + 1);
      const float* rp = emb + row * D_ + lane * 4;
      gl2lds(rp, wsl + i * D_);
      gl2lds(rp + 256, wsl + i * D_ + 256);
    }
#pragma unroll
    for (int i = 0; i < 32; ++i) {
      ring_wait(i);
      const float4* sp = (const float4*)(wsl + (i & (NS_ - 1)) * D_);
      const float4 e0 = sp[lane];
      const float4 e1 = sp[lane + 64];
      const float sc = wave_sum_u(dot8(e0, e1, a0, a1));
      const float mn = fmaxf(m, sc);
      const float al = __expf(m - mn);
      const float p  = __expf(sc - mn);
      s = s * al + p;
      acc[0] = acc[0] * al + p * e0.x; acc[1] = acc[1] * al + p * e0.y;
      acc[2] = acc[2] * al + p * e0.z; acc[3] = acc[3] * al + p * e0.w;
      acc[4] = acc[4] * al + p * e1.x; acc[5] = acc[5] * al + p * e1.y;
      acc[6] = acc[6] * al + p * e1.z; acc[7] = acc[7] * al + p * e1.w;
      m = mn;
      if (i + NS_ < 32) {
        const size_t row = (size_t)(__builtin_amdgcn_readlane(tokv, i + NS_) + 1);
        const float* rp = emb + row * D_ + lane * 4;
        float* sl = wsl + (i & (NS_ - 1)) * D_;
        gl2lds(rp, sl);
        gl2lds(rp + 256, sl + 256);
      }
    }
    if (lane == 0) { red[w][0] = m; red[w][1] = s; }
    __syncthreads();                          // rings idle + red visible
    const float M = fmaxf(fmaxf(red[0][0], red[1][0]), fmaxf(red[2][0], red[3][0]));
    const float scw = __expf(m - M);          // m is wave-uniform
    float* buf = stag;                        // overlay combine buffer
#pragma unroll
    for (int j = 0; j < 4; ++j) {
      buf[w * D_ + lane * 4 + j]       = acc[j] * scw;
      buf[w * D_ + 256 + lane * 4 + j] = acc[4 + j] * scw;
    }
    __syncthreads();
    const int c = 2 * t;
    const float o0 = buf[c] + buf[D_ + c] + buf[2 * D_ + c] + buf[3 * D_ + c];
    const float o1 = buf[c + 1] + buf[D_ + c + 1] + buf[2 * D_ + c + 1] + buf[3 * D_ + c + 1];
    float* oa = A + ((size_t)seg * B_ + b) * D_;   // overwrite h-partials (consumed)
    oa[c] = o0; oa[c + 1] = o1;
    if (t == 0) {
      float st = red[0][1] * __expf(red[0][0] - M) + red[1][1] * __expf(red[1][0] - M)
               + red[2][1] * __expf(red[2][0] - M) + red[3][1] * __expf(red[3][0] - M);
      ms[((size_t)seg * B_ + b) * 2]     = M;
      ms[((size_t)seg * B_ + b) * 2 + 1] = st;
    }
    __syncthreads();                          // combine reads done before reuse
  }
  gbar(bar + 2);

  // ---------------- phase D: merge segment partials -> out ----------
  if (bid < B_) {
    const int b = bid;
    float* wseg = stag;                       // overlay: SEG_ weights
    if (t == 0) {
      float M = -1e30f;
#pragma unroll
      for (int s = 0; s < SEG_; ++s) M = fmaxf(M, ms[((size_t)s * B_ + b) * 2]);
      float den = 0.f;
#pragma unroll
      for (int s = 0; s < SEG_; ++s)
        den += ms[((size_t)s * B_ + b) * 2 + 1] * __expf(ms[((size_t)s * B_ + b) * 2] - M);
      const float inv = 1.f / den;
#pragma unroll
      for (int s = 0; s < SEG_; ++s)
        wseg[s] = __expf(ms[((size_t)s * B_ + b) * 2] - M) * inv;
    }
    __syncthreads();
    const int c = 2 * t;
    float o0 = 0.f, o1 = 0.f;
#pragma unroll
    for (int s = 0; s < SEG_; ++s) {
      const float* oa = A + ((size_t)s * B_ + b) * D_;
      const float ww = wseg[s];
      o0 += ww * oa[c]; o1 += ww * oa[c + 1];
    }
    out[(size_t)b * D_ + c] = o0;
    out[(size_t)b * D_ + c + 1] = o1;
  }
}

// ---------- launch ----------
extern "C" void kernel_launch(void* const* d_in, const int* in_sizes, int n_in,
                              void* d_out, int out_size, void* d_ws, size_t ws_size,
                              hipStream_t stream) {
  const int* tok = (const int*)d_in[0];
  const float* emb = (const float*)d_in[1];
  const float* Wb  = (const float*)d_in[2];
  float* out = (float*)d_out;
  float* ws = (float*)d_ws;

  float* A  = ws;              // SEG_*B_*D_ = 524288 floats
  float* v  = ws + 524288;     // B_*D_
  float* ms = v + 32768;       // SEG_*B_*2
  unsigned* bar = (unsigned*)(ms + 2048);   // 3 barrier counters

  hipMemsetAsync(bar, 0, 16, stream);       // counters must start at 0 each run
  k_fused<<<NB_, 256, 0, stream>>>(tok, emb, Wb, A, v, ms, out, bar);
}

// Round 5
// 296.984 us; speedup vs baseline: 1.4023x; 1.4023x over previous
//
#include <hip/hip_runtime.h>

#define B_   64
#define L_   2048
#define D_   512
#define SEG_ 16         // segments over L for the two passes
#define RPS_ 128        // rows per segment (L_/SEG_)
#define NS_  4          // LDS ring slots per wave (2KB fp32 row each)

// counted vmem wait; "memory" clobber keeps following ds_read from hoisting
#define WAITVM(N) asm volatile("s_waitcnt vmcnt(" #N ")" ::: "memory")

// async global->LDS DMA: 16B/lane, 64 lanes -> 1KB per call
__device__ __forceinline__ void gl2lds(const float* g, float* l) {
  __builtin_amdgcn_global_load_lds(
      (const __attribute__((address_space(1))) void*)g,
      (__attribute__((address_space(3))) void*)l, 16, 0, 0);
}

// DPP add step: x += dpp_move(x, C); bound_ctrl -> invalid lanes contribute 0
template <int C>
__device__ __forceinline__ float dpp_add(float x) {
  int y = __builtin_amdgcn_update_dpp(0, __builtin_bit_cast(int, x), C, 0xf, 0xf, true);
  return x + __builtin_bit_cast(float, y);
}

// full 64-lane sum, VALU-pipe only; uniform result via readlane 63
__device__ __forceinline__ float wave_sum_u(float x) {
  x = dpp_add<0x111>(x);   // row_shr:1
  x = dpp_add<0x112>(x);   // row_shr:2
  x = dpp_add<0x114>(x);   // row_shr:4
  x = dpp_add<0x118>(x);   // row_shr:8
  x = dpp_add<0x142>(x);   // row_bcast15
  x = dpp_add<0x143>(x);   // row_bcast31 -> lane 63 has full sum
  return __builtin_bit_cast(float, __builtin_amdgcn_readlane(__builtin_bit_cast(int, x), 63));
}

__device__ __forceinline__ float dot8(float4 e0, float4 e1, float4 a0, float4 a1) {
  return e0.x * a0.x + e0.y * a0.y + e0.z * a0.z + e0.w * a0.w +
         e1.x * a1.x + e1.y * a1.y + e1.z * a1.z + e1.w * a1.w;
}

// tail-drain schedule for NS_=4 ring (2 loads/row). With interleaved stores
// the invariant still holds: at iter i's wait, the newest <=6 outstanding ops
// were all issued after row i's loads, so row i's loads have retired.
__device__ __forceinline__ void ring_wait(int i) {
  if (i <= 28)      WAITVM(6);
  else if (i == 29) WAITVM(4);
  else if (i == 30) WAITVM(2);
  else              WAITVM(0);
}

// ---------- K1: gather rows -> h-partials (+ optional sequential copy) ----------
// grid (SEG_, B_) = 1024 blocks, 4 waves. Per wave: 32 rows through a private
// 4-slot LDS ring. If STORE, each row is also streamed to Eseq (coalesced 2KB)
// so the second pass reads linearly instead of re-gathering.
template <bool STORE>
__global__ __launch_bounds__(256) void k_hpart(const int* __restrict__ tok,
                                               const float* __restrict__ emb,
                                               float* __restrict__ Eseq,
                                               float* __restrict__ A) {
  const int seg = blockIdx.x, b = blockIdx.y;
  const int t = threadIdx.x, w = t >> 6, lane = t & 63;
  __shared__ __align__(16) float stag[4 * NS_ * D_];   // 32 KB ring / overlay
  float* wsl = stag + w * (NS_ * D_);
  const int tokv = tok[b * L_ + seg * RPS_ + w * 32 + (lane & 31)];
  const size_t rowbase = (size_t)b * L_ + seg * RPS_ + w * 32;
  float acc[8];
#pragma unroll
  for (int j = 0; j < 8; ++j) acc[j] = 0.f;
#pragma unroll
  for (int i = 0; i < NS_; ++i) {
    const size_t row = (size_t)(__builtin_amdgcn_readlane(tokv, i) + 1);
    const float* rp = emb + row * D_ + lane * 4;
    gl2lds(rp, wsl + i * D_);
    gl2lds(rp + 256, wsl + i * D_ + 256);
  }
#pragma unroll
  for (int i = 0; i < 32; ++i) {
    ring_wait(i);
    const float4* sp = (const float4*)(wsl + (i & (NS_ - 1)) * D_);
    const float4 e0 = sp[lane];
    const float4 e1 = sp[lane + 64];
    acc[0] += e0.x; acc[1] += e0.y; acc[2] += e0.z; acc[3] += e0.w;
    acc[4] += e1.x; acc[5] += e1.y; acc[6] += e1.z; acc[7] += e1.w;
    if (STORE) {   // sequential copy-out: 2KB contiguous per row, coalesced
      float4* dst = (float4*)(Eseq + (rowbase + i) * D_);
      dst[lane]      = e0;
      dst[lane + 64] = e1;
    }
    if (i + NS_ < 32) {
      const size_t row = (size_t)(__builtin_amdgcn_readlane(tokv, i + NS_) + 1);
      const float* rp = emb + row * D_ + lane * 4;
      float* sl = wsl + (i & (NS_ - 1)) * D_;
      gl2lds(rp, sl);
      gl2lds(rp + 256, sl + 256);
    }
  }
  __syncthreads();                          // all waves' rings idle
  float* buf = stag;                        // overlay: 4 x D_ combine buffer
#pragma unroll
  for (int j = 0; j < 4; ++j) {
    buf[w * D_ + lane * 4 + j]       = acc[j];
    buf[w * D_ + 256 + lane * 4 + j] = acc[4 + j];
  }
  __syncthreads();
  const int c = 2 * t;
  const float s0 = buf[c] + buf[D_ + c] + buf[2 * D_ + c] + buf[3 * D_ + c];
  const float s1 = buf[c + 1] + buf[D_ + c + 1] + buf[2 * D_ + c + 1] + buf[3 * D_ + c + 1];
  float* o = A + ((size_t)seg * B_ + b) * D_;
  o[c] = s0; o[c + 1] = s1;
}

// ---------- K2: v[b] = W_b @ h[b] / L ----------
__global__ __launch_bounds__(256) void k_v(const float* __restrict__ A,
                                           const float* __restrict__ Wb,
                                           float* __restrict__ v) {
  const int g = blockIdx.x, b = blockIdx.y;
  const int t = threadIdx.x, w = t >> 6, lane = t & 63;
  __shared__ float sh[D_];
  float s0 = 0.f, s1 = 0.f;
#pragma unroll
  for (int s = 0; s < SEG_; ++s) {
    const float* hp = A + ((size_t)s * B_ + b) * D_;
    s0 += hp[2 * t]; s1 += hp[2 * t + 1];
  }
  sh[2 * t] = s0; sh[2 * t + 1] = s1;
  __syncthreads();
  const float4* shv = (const float4*)sh;
  const float4 a0 = shv[lane];
  const float4 a1 = shv[lane + 64];
  const int d0 = g * 64 + w * 16;
#pragma unroll 4
  for (int i = 0; i < 16; ++i) {
    const int d = d0 + i;
    const float4* rp = (const float4*)(Wb + (size_t)d * D_);
    const float r = wave_sum_u(dot8(rp[lane], rp[lane + 64], a0, a1));
    if (lane == 0) v[(size_t)b * D_ + d] = r * (1.f / (float)L_);
  }
}

// ---------- K3: scores+softmax+weighted-sum ----------
// LINEAR=true: stream contiguous Eseq slice (no indirection).
// LINEAR=false: re-gather rows from emb via tok (fallback, small-ws path).
template <bool LINEAR>
__global__ __launch_bounds__(256) void k_flash(const int* __restrict__ tok,
                                               const float* __restrict__ Esrc,
                                               const float* __restrict__ v,
                                               float* __restrict__ A,
                                               float* __restrict__ ms) {
  const int seg = blockIdx.x, b = blockIdx.y;
  const int t = threadIdx.x, w = t >> 6, lane = t & 63;
  __shared__ __align__(16) float stag[4 * NS_ * D_];   // 32 KB ring / overlay
  __shared__ float red[4][2];
  float* wsl = stag + w * (NS_ * D_);
  const int tokv = LINEAR ? 0 : tok[b * L_ + seg * RPS_ + w * 32 + (lane & 31)];
  const float* lsrc = Esrc + ((size_t)b * L_ + seg * RPS_ + w * 32) * D_;
  const float4* vv = (const float4*)(v + (size_t)b * D_);
  const float4 a0 = vv[lane];
  const float4 a1 = vv[lane + 64];
  float m = -1e30f, s = 0.f;
  float acc[8];
#pragma unroll
  for (int j = 0; j < 8; ++j) acc[j] = 0.f;
#pragma unroll
  for (int i = 0; i < NS_; ++i) {
    const float* rp = LINEAR
        ? lsrc + (size_t)i * D_ + lane * 4
        : Esrc + (size_t)(__builtin_amdgcn_readlane(tokv, i) + 1) * D_ + lane * 4;
    gl2lds(rp, wsl + i * D_);
    gl2lds(rp + 256, wsl + i * D_ + 256);
  }
#pragma unroll
  for (int i = 0; i < 32; ++i) {
    ring_wait(i);
    const float4* sp = (const float4*)(wsl + (i & (NS_ - 1)) * D_);
    const float4 e0 = sp[lane];
    const float4 e1 = sp[lane + 64];
    const float sc = wave_sum_u(dot8(e0, e1, a0, a1));
    const float mn = fmaxf(m, sc);
    const float al = __expf(m - mn);
    const float p  = __expf(sc - mn);
    s = s * al + p;
    acc[0] = acc[0] * al + p * e0.x; acc[1] = acc[1] * al + p * e0.y;
    acc[2] = acc[2] * al + p * e0.z; acc[3] = acc[3] * al + p * e0.w;
    acc[4] = acc[4] * al + p * e1.x; acc[5] = acc[5] * al + p * e1.y;
    acc[6] = acc[6] * al + p * e1.z; acc[7] = acc[7] * al + p * e1.w;
    m = mn;
    if (i + NS_ < 32) {
      const float* rp = LINEAR
          ? lsrc + (size_t)(i + NS_) * D_ + lane * 4
          : Esrc + (size_t)(__builtin_amdgcn_readlane(tokv, i + NS_) + 1) * D_ + lane * 4;
      float* sl = wsl + (i & (NS_ - 1)) * D_;
      gl2lds(rp, sl);
      gl2lds(rp + 256, sl + 256);
    }
  }
  if (lane == 0) { red[w][0] = m; red[w][1] = s; }
  __syncthreads();                          // rings idle + red visible
  const float M = fmaxf(fmaxf(red[0][0], red[1][0]), fmaxf(red[2][0], red[3][0]));
  const float scw = __expf(m - M);          // m is wave-uniform
  float* buf = stag;                        // overlay combine buffer
#pragma unroll
  for (int j = 0; j < 4; ++j) {
    buf[w * D_ + lane * 4 + j]       = acc[j] * scw;
    buf[w * D_ + 256 + lane * 4 + j] = acc[4 + j] * scw;
  }
  __syncthreads();
  const int c = 2 * t;
  const float o0 = buf[c] + buf[D_ + c] + buf[2 * D_ + c] + buf[3 * D_ + c];
  const float o1 = buf[c + 1] + buf[D_ + c + 1] + buf[2 * D_ + c + 1] + buf[3 * D_ + c + 1];
  float* oa = A + ((size_t)seg * B_ + b) * D_;   // overwrite h-partials (consumed)
  oa[c] = o0; oa[c + 1] = o1;
  if (t == 0) {
    float st = red[0][1] * __expf(red[0][0] - M) + red[1][1] * __expf(red[1][0] - M)
             + red[2][1] * __expf(red[2][0] - M) + red[3][1] * __expf(red[3][0] - M);
    ms[((size_t)seg * B_ + b) * 2]     = M;
    ms[((size_t)seg * B_ + b) * 2 + 1] = st;
  }
}

// ---------- K4: merge segment partials -> out ----------
__global__ __launch_bounds__(256) void k_merge(const float* __restrict__ A,
                                               const float* __restrict__ ms,
                                               float* __restrict__ out) {
  const int b = blockIdx.x;
  const int t = threadIdx.x;
  __shared__ float wseg[SEG_];
  if (t == 0) {
    float M = -1e30f;
#pragma unroll
    for (int s = 0; s < SEG_; ++s) M = fmaxf(M, ms[((size_t)s * B_ + b) * 2]);
    float den = 0.f;
#pragma unroll
    for (int s = 0; s < SEG_; ++s)
      den += ms[((size_t)s * B_ + b) * 2 + 1] * __expf(ms[((size_t)s * B_ + b) * 2] - M);
    const float inv = 1.f / den;
#pragma unroll
    for (int s = 0; s < SEG_; ++s)
      wseg[s] = __expf(ms[((size_t)s * B_ + b) * 2] - M) * inv;
  }
  __syncthreads();
  const int c = 2 * t;
  float o0 = 0.f, o1 = 0.f;
#pragma unroll
  for (int s = 0; s < SEG_; ++s) {
    const float* oa = A + ((size_t)s * B_ + b) * D_;
    const float ww = wseg[s];
    o0 += ww * oa[c]; o1 += ww * oa[c + 1];
  }
  out[(size_t)b * D_ + c] = o0;
  out[(size_t)b * D_ + c + 1] = o1;
}

// ---------- launch ----------
extern "C" void kernel_launch(void* const* d_in, const int* in_sizes, int n_in,
                              void* d_out, int out_size, void* d_ws, size_t ws_size,
                              hipStream_t stream) {
  const int* tok = (const int*)d_in[0];
  const float* emb = (const float*)d_in[1];
  const float* Wb  = (const float*)d_in[2];
  float* out = (float*)d_out;
  float* ws = (float*)d_ws;

  // Eseq path needs (Eseq + A + v + ms) floats:
  const size_t nEseq = (size_t)B_ * L_ * D_;            // 67,108,864
  const size_t need  = (nEseq + 524288 + 32768 + 2048) * sizeof(float); // ~258.2 MB

  if (ws_size >= need) {
    float* Eseq = ws;
    float* A    = ws + nEseq;
    float* v    = A + 524288;
    float* ms   = v + 32768;
    k_hpart<true> <<<dim3(SEG_, B_), 256, 0, stream>>>(tok, emb, Eseq, A);
    k_v           <<<dim3(8, B_),    256, 0, stream>>>(A, Wb, v);
    k_flash<true> <<<dim3(SEG_, B_), 256, 0, stream>>>(tok, Eseq, v, A, ms);
    k_merge       <<<B_,             256, 0, stream>>>(A, ms, out);
  } else {
    // small-ws fallback: double-gather (R0-equivalent numerics and traffic)
    float* A  = ws;
    float* v  = ws + 524288;
    float* ms = v + 32768;
    k_hpart<false><<<dim3(SEG_, B_), 256, 0, stream>>>(tok, emb, nullptr, A);
    k_v           <<<dim3(8, B_),    256, 0, stream>>>(A, Wb, v);
    k_flash<false><<<dim3(SEG_, B_), 256, 0, stream>>>(tok, emb, v, A, ms);
    k_merge       <<<B_,             256, 0, stream>>>(A, ms, out);
  }
}